// Round 9
// baseline (585.619 us; speedup 1.0000x reference)
//
#include <hip/hip_runtime.h>
#include <hip/hip_bf16.h>
#include <stdint.h>

#define E_ 8
#define M_ 8192
#define K_ 2048
#define N_ 8192

#define BM 128
#define BN 256
#define BK 64
#define NT (K_ / BK)        // 32 K-tiles
#define TILE_B 49152        // A 16KB + B 32KB
#define LDS_BYTES 98304     // 2 dbuf x 48KB

typedef __attribute__((ext_vector_type(8))) short bf16x8;
typedef __attribute__((ext_vector_type(4))) float f32x4;
typedef __attribute__((ext_vector_type(8))) unsigned short us8;

__device__ __forceinline__ unsigned short f2bf(float f) {
  union { float f; uint32_t u; } v; v.f = f;
  uint32_t u = v.u;
  uint32_t r = (u + 0x7FFFu + ((u >> 16) & 1u)) >> 16;
  return (unsigned short)r;
}

__device__ __forceinline__ unsigned short f2bf_hw(float f) {
  union { __hip_bfloat16 h; unsigned short u; } v;
  v.h = __float2bfloat16(f);   // RNE; pairs fuse to v_cvt_pk_bf16_f32
  return v.u;
}

__device__ __forceinline__ void gload_lds16(const void* g, void* l) {
  __builtin_amdgcn_global_load_lds(
      (const __attribute__((address_space(1))) unsigned int*)g,
      (__attribute__((address_space(3))) unsigned int*)l,
      16, 0, 0);
}

// ---------------- fp32 -> bf16, layout preserving (inputs) ----------------
__global__ __launch_bounds__(256) void conv_a(const float* __restrict__ A,
                                              unsigned short* __restrict__ Ab,
                                              int n8) {
  int stride = gridDim.x * blockDim.x;
  for (int idx = blockIdx.x * blockDim.x + threadIdx.x; idx < n8; idx += stride) {
    const float4* p = reinterpret_cast<const float4*>(A) + (size_t)idx * 2;
    float4 x0 = p[0], x1 = p[1];
    us8 o;
    o[0] = f2bf(x0.x); o[1] = f2bf(x0.y); o[2] = f2bf(x0.z); o[3] = f2bf(x0.w);
    o[4] = f2bf(x1.x); o[5] = f2bf(x1.y); o[6] = f2bf(x1.z); o[7] = f2bf(x1.w);
    *reinterpret_cast<us8*>(Ab + (size_t)idx * 8) = o;
  }
}

// ---- grouped GEMM 128x256, BK=64, fused W fp32->bf16 (no conv_wT pass) ----
// LDS dbuf d at d*49152: A @0 (128 rows x 128B), B @16384 (256 rows x 128B).
// Row r: 8 slots of 16B; logical k-quarter q at phys slot q ^ (r&7)
// (R2-verified conflict-free read pattern). 2 phases per K-tile (ks0, ks1),
// 16 MFMA each; acc = 64 AGPR/wave -> 64 free VGPRs fund the B reg-pipeline.
// B pipeline (lag = 2 long phases ~1000cy): tile t P0: load B(t+2).g0, cvt+write
// B(t+1).g0 (loaded t-1); P1: same for g1. A via gload_lds at P0 (lag 2 phases).
// End-of-tile: counted vmcnt(16) drains only A gloads. Never 0 in loop.
__global__ __launch_bounds__(512, 2) void moe_gemm_fused(
    const unsigned short* __restrict__ Ab,   // [M][K] bf16
    const float* __restrict__ W,             // [E][K][N] fp32
    const int* __restrict__ gs,
    const float* __restrict__ bias,
    float* __restrict__ C) {
  extern __shared__ char smem[];

  int tile_n = blockIdx.x;
  int tile_m = blockIdx.y;

  // map row-tile -> (expert, row_start, rows); wave-uniform scalar scan
  int expert = -1, row_start = 0, rows = 0;
  {
    int acc = 0, off = 0;
    for (int e = 0; e < E_; ++e) {
      int g = gs[e];
      int t = (g + BM - 1) / BM;
      if (expert < 0 && tile_m < acc + t) {
        int lt = tile_m - acc;
        expert = e;
        row_start = off + lt * BM;
        rows = min(BM, g - lt * BM);
      }
      acc += t;
      off += g;
    }
    if (expert < 0) return;
  }

  const float* WfE = W + (size_t)expert * K_ * N_;

  int tid = threadIdx.x;          // 0..511
  int lane = tid & 63;
  int wave = tid >> 6;            // 0..7
  int wr = wave >> 2;             // 0..1 (M half: 64 rows)
  int wc = wave & 3;              // 0..3 (N quarter: 64 cols)
  int ln15 = lane & 15;
  int n0 = tile_n * BN;

  // ---- fragment read bases (phys slot = logical ^ (row&7)) ----
  int slot0 = (((lane >> 4) ^ (ln15 & 7)) << 4);   // ks1 = ^64
  int aBase = wr * 8192 + ln15 * 128;              // + mi*2048
  int bBase = 16384 + wc * 8192 + ln15 * 128;      // + nj*2048

  // ---- A staging: thread stages 16B of each 8KB (64-row) chunk ----
  int soff = tid * 16;
  int crow = tid >> 3;            // 0..63
  int lslot = (tid & 7) ^ (crow & 7);
  int scolA = lslot * 8;
  const unsigned short* aS[2];
  #pragma unroll
  for (int c = 0; c < 2; ++c) {
    int r = c * 64 + crow;
    int gr = r < rows ? r : 0;    // clamp partial M tiles
    aS[c] = Ab + (size_t)(row_start + gr) * K_ + scolA;
  }
#define STG_A(DB, c, kt) \
  gload_lds16(aS[c] + (kt) * 64, smem + (DB) + (c) * 8192 + soff)

  // ---- B fused staging: thread owns rows {nB, nB+1}, k-units kb0 / kb0+4 ----
  int nB = (tid & 127) * 2;       // even row 0..254
  int kb0 = tid >> 7;             // 0..3
  const float* wB = WfE + (size_t)(n0 + nB);       // + k * N_
  int bwE0 = 16384 + nB * 128 + ((kb0 ^ (nB & 7)) << 4);
  int bwO0 = 16384 + (nB + 1) * 128 + ((kb0 ^ ((nB + 1) & 7)) << 4);
  int bwE1 = 16384 + nB * 128 + (((kb0 + 4) ^ (nB & 7)) << 4);
  int bwO1 = 16384 + (nB + 1) * 128 + (((kb0 + 4) ^ ((nB + 1) & 7)) << 4);

  // two reg-set pairs (16 regs each), swapped by tile parity; static-indexed
  float2 sP0[8], sP1[8], sQ0[8], sQ1[8];

#define LOAD_B(arr, KB, KT)                                                   \
  _Pragma("unroll") for (int j = 0; j < 8; ++j)                               \
    arr[j] = *(const float2*)(wB + (size_t)((KT) * 64 + (KB) * 8 + j) * N_);

#define CVT_WRITE(arr, WE, WO, DBN)                                           \
  do {                                                                        \
    us8 oe, oo;                                                               \
    _Pragma("unroll") for (int p = 0; p < 8; ++p) {                           \
      oe[p] = f2bf_hw(arr[p].x);                                              \
      oo[p] = f2bf_hw(arr[p].y);                                              \
    }                                                                         \
    *(us8*)(smem + (DBN) + (WE)) = oe;                                        \
    *(us8*)(smem + (DBN) + (WO)) = oo;                                        \
  } while (0)

  f32x4 acc4[4][4];
  #pragma unroll
  for (int i = 0; i < 4; ++i)
    #pragma unroll
    for (int j = 0; j < 4; ++j)
      acc4[i][j] = f32x4{0.f, 0.f, 0.f, 0.f};

#define DS_A(frag, DB, KS)                                                    \
  _Pragma("unroll") for (int mi = 0; mi < 4; ++mi)                            \
    frag[mi] = *(const bf16x8*)(smem + (DB) + aBase + mi * 2048 +             \
                                (slot0 ^ ((KS) << 6)));
#define DS_B(frag, DB, KS)                                                    \
  _Pragma("unroll") for (int nj = 0; nj < 4; ++nj)                            \
    frag[nj] = *(const bf16x8*)(smem + (DB) + bBase + nj * 2048 +             \
                                (slot0 ^ ((KS) << 6)));
#define MFMA16(af, bf)                                                        \
  __builtin_amdgcn_s_setprio(1);                                              \
  _Pragma("unroll") for (int mi = 0; mi < 4; ++mi)                            \
    _Pragma("unroll") for (int nj = 0; nj < 4; ++nj)                          \
      acc4[mi][nj] = __builtin_amdgcn_mfma_f32_16x16x32_bf16(                 \
          af[mi], bf[nj], acc4[mi][nj], 0, 0, 0);                             \
  __builtin_amdgcn_s_setprio(0);

  // Per K-tile: P0 (ks0), P1 (ks1); 16 MFMA each.
  // L0/L1: sets receiving B(t+2); Wr0/Wr1: sets holding B(t+1) (loaded t-1).
#define TILE2(DB, DBN, Wr0, Wr1, L0, L1, KTA, KTB)                            \
  do {                                                                        \
    bf16x8 af[4], bf[4];                                                      \
    /* P0: ks0 */                                                             \
    DS_A(af, DB, 0); DS_B(bf, DB, 0);                                         \
    STG_A(DBN, 0, KTA); STG_A(DBN, 1, KTA);                                   \
    LOAD_B(L0, kb0, KTB);                                                     \
    CVT_WRITE(Wr0, bwE0, bwO0, DBN);                                          \
    __builtin_amdgcn_sched_barrier(0);                                        \
    __builtin_amdgcn_s_barrier();                                             \
    asm volatile("s_waitcnt lgkmcnt(0)" ::: "memory");                        \
    __builtin_amdgcn_sched_barrier(0);                                        \
    MFMA16(af, bf);                                                           \
    __builtin_amdgcn_s_barrier();                                             \
    /* P1: ks1 */                                                             \
    DS_A(af, DB, 1); DS_B(bf, DB, 1);                                         \
    LOAD_B(L1, kb0 + 4, KTB);                                                 \
    CVT_WRITE(Wr1, bwE1, bwO1, DBN);                                          \
    __builtin_amdgcn_sched_barrier(0);                                        \
    __builtin_amdgcn_s_barrier();                                             \
    asm volatile("s_waitcnt lgkmcnt(0)" ::: "memory");                        \
    __builtin_amdgcn_sched_barrier(0);                                        \
    MFMA16(af, bf);                                                           \
    asm volatile("s_waitcnt vmcnt(16)" ::: "memory"); /* drain A(t+1) only */ \
    __builtin_amdgcn_s_barrier();                                             \
  } while (0)

  // prologue: A(0) + B(0) (via sP) -> buf0; B(1) -> sQ (left in flight)
  STG_A(0, 0, 0); STG_A(0, 1, 0);
  LOAD_B(sP0, kb0, 0); LOAD_B(sP1, kb0 + 4, 0);
  __builtin_amdgcn_sched_barrier(0);
  CVT_WRITE(sP0, bwE0, bwO0, 0);    // auto-waits sP loads; drains A(0) too (FIFO)
  CVT_WRITE(sP1, bwE1, bwO1, 0);
  LOAD_B(sQ0, kb0, 1); LOAD_B(sQ1, kb0 + 4, 1);
  __builtin_amdgcn_sched_barrier(0);
  asm volatile("s_waitcnt lgkmcnt(0)" ::: "memory");
  __builtin_amdgcn_s_barrier();

  for (int t2 = 0; t2 < NT; t2 += 2) {
    int k2 = (t2 + 2 >= NT) ? 0 : t2 + 2;   // wrap: dead loads, uniform counts
    int k3 = (t2 + 3 >= NT) ? 0 : t2 + 3;
    // even tile t2: write sQ (B(t2+1)), load sP <- B(t2+2)
    TILE2(0, TILE_B, sQ0, sQ1, sP0, sP1, t2 + 1, k2);
    // odd tile t2+1: write sP (B(t2+2)), load sQ <- B(t2+3)
    TILE2(TILE_B, 0, sP0, sP1, sQ0, sQ1, k2, k3);
  }
#undef TILE2
#undef DS_A
#undef DS_B
#undef MFMA16
#undef STG_A
#undef LOAD_B
#undef CVT_WRITE

  asm volatile("s_waitcnt vmcnt(0)" ::: "memory");  // drain dead tail stages

  // epilogue: C = acc + bias ; C/D layout col=lane&15, row=(lane>>4)*4+reg
  float bv[4];
  #pragma unroll
  for (int nj = 0; nj < 4; ++nj) bv[nj] = bias[n0 + wc * 64 + nj * 16 + ln15];
  #pragma unroll
  for (int mi = 0; mi < 4; ++mi) {
    int r0 = wr * 64 + mi * 16 + (lane >> 4) * 4;
    #pragma unroll
    for (int r = 0; r < 4; ++r) {
      int lr = r0 + r;
      if (lr < rows) {
        float* Cp = C + (size_t)(row_start + lr) * N_ + n0 + wc * 64 + ln15;
        #pragma unroll
        for (int nj = 0; nj < 4; ++nj) Cp[nj * 16] = acc4[mi][nj][r] + bv[nj];
      }
    }
  }
}

// ---------------- naive fp32 fallback (only if workspace too small) ----------------
__global__ __launch_bounds__(256) void moe_naive(const float* __restrict__ A,
                                                 const float* __restrict__ W,
                                                 const int* __restrict__ gs,
                                                 const float* __restrict__ bias,
                                                 float* __restrict__ C) {
  int col = blockIdx.x * 16 + (threadIdx.x & 15);
  int row = blockIdx.y * 16 + (threadIdx.x >> 4);
  int acc = 0, e = E_ - 1;
  for (int i = 0; i < E_; ++i) {
    int g = gs[i];
    if (row >= acc && row < acc + g) { e = i; break; }
    acc += g;
  }
  const float* a = A + (size_t)row * K_;
  const float* w = W + (size_t)e * K_ * N_ + col;
  float s = 0.f;
  for (int k = 0; k < K_; ++k) s += a[k] * w[(size_t)k * N_];
  C[(size_t)row * N_ + col] = s + bias[col];
}

extern "C" void kernel_launch(void* const* d_in, const int* in_sizes, int n_in,
                              void* d_out, int out_size, void* d_ws, size_t ws_size,
                              hipStream_t stream) {
  const float* A = (const float*)d_in[0];
  const float* W = (const float*)d_in[1];
  const int* gs = (const int*)d_in[2];
  const float* bias = (const float*)d_in[3];
  float* C = (float*)d_out;

  const size_t needA = (size_t)M_ * K_ * 2;  // 32 MiB

  (void)hipFuncSetAttribute((const void*)moe_gemm_fused,
                            hipFuncAttributeMaxDynamicSharedMemorySize, LDS_BYTES);

  if (ws_size >= needA) {
    unsigned short* Abf = (unsigned short*)d_ws;
    conv_a<<<2048, 256, 0, stream>>>(A, Abf, (M_ * K_) / 8);
    dim3 gg(N_ / BN, M_ / BM + E_);
    moe_gemm_fused<<<gg, 512, LDS_BYTES, stream>>>(Abf, W, gs, bias, C);
  } else {
    dim3 gn(N_ / 16, M_ / 16);
    moe_naive<<<gn, 256, 0, stream>>>(A, W, gs, bias, C);
  }
}

// Round 10
// 575.266 us; speedup vs baseline: 1.0180x; 1.0180x over previous
//
#include <hip/hip_runtime.h>
#include <hip/hip_bf16.h>
#include <stdint.h>

#define E_ 8
#define M_ 8192
#define K_ 2048
#define N_ 8192

#define BM 128
#define BN 256
#define BK 64
#define NT (K_ / BK)        // 32 K-tiles
#define TILE_B 49152        // A 16KB + B 32KB
#define LDS_BYTES 98304     // 2 dbuf x 48KB

typedef __attribute__((ext_vector_type(8))) short bf16x8;
typedef __attribute__((ext_vector_type(4))) float f32x4;
typedef __attribute__((ext_vector_type(8))) unsigned short us8;

__device__ __forceinline__ unsigned short f2bf(float f) {
  union { float f; uint32_t u; } v; v.f = f;
  uint32_t u = v.u;
  uint32_t r = (u + 0x7FFFu + ((u >> 16) & 1u)) >> 16;
  return (unsigned short)r;
}

__device__ __forceinline__ unsigned short f2bf_hw(float f) {
  union { __hip_bfloat16 h; unsigned short u; } v;
  v.h = __float2bfloat16(f);   // RNE; pairs fuse to v_cvt_pk_bf16_f32
  return v.u;
}

__device__ __forceinline__ void gload_lds16(const void* g, void* l) {
  __builtin_amdgcn_global_load_lds(
      (const __attribute__((address_space(1))) unsigned int*)g,
      (__attribute__((address_space(3))) unsigned int*)l,
      16, 0, 0);
}

// ---------------- fp32 -> bf16, layout preserving (inputs) ----------------
__global__ __launch_bounds__(256) void conv_a(const float* __restrict__ A,
                                              unsigned short* __restrict__ Ab,
                                              int n8) {
  int stride = gridDim.x * blockDim.x;
  for (int idx = blockIdx.x * blockDim.x + threadIdx.x; idx < n8; idx += stride) {
    const float4* p = reinterpret_cast<const float4*>(A) + (size_t)idx * 2;
    float4 x0 = p[0], x1 = p[1];
    us8 o;
    o[0] = f2bf(x0.x); o[1] = f2bf(x0.y); o[2] = f2bf(x0.z); o[3] = f2bf(x0.w);
    o[4] = f2bf(x1.x); o[5] = f2bf(x1.y); o[6] = f2bf(x1.z); o[7] = f2bf(x1.w);
    *reinterpret_cast<us8*>(Ab + (size_t)idx * 8) = o;
  }
}

// ---- grouped GEMM 128x256, BK=64, fused W fp32->bf16 (no conv_wT pass) ----
// LDS dbuf d at d*49152: A @0 (128 rows x 128B), B @16384 (256 rows x 128B).
// Row r: 8 slots of 16B; logical k-quarter q at phys slot q ^ ((r>>1)&7)
// (R6 swizzle - measured 0 bank conflicts for BOTH this read pattern and the
// even/odd-row-pair ds_write_b128 pattern; R9's r&7 was a 4-way write conflict).
// 2 phases/K-tile (ks0,ks1), 16 MFMA each; acc=64 AGPR/wave.
// B pipeline lag = 2 long phases (~1000cy): tile t P0: load B(t+2).g0,
// cvt+write B(t+1).g0 (loaded t-1); P1 same for g1. A via gload_lds at P0.
// End-of-tile: counted vmcnt(16) drains only the 2 A gloads (order pinned by
// sched_barrier so A precedes B in the VMEM FIFO). Never 0 in loop.
__global__ __launch_bounds__(512, 2) void moe_gemm_fused(
    const unsigned short* __restrict__ Ab,   // [M][K] bf16
    const float* __restrict__ W,             // [E][K][N] fp32
    const int* __restrict__ gs,
    const float* __restrict__ bias,
    float* __restrict__ C) {
  extern __shared__ char smem[];

  int tile_n = blockIdx.x;
  int tile_m = blockIdx.y;

  // map row-tile -> (expert, row_start, rows); wave-uniform scalar scan
  int expert = -1, row_start = 0, rows = 0;
  {
    int acc = 0, off = 0;
    for (int e = 0; e < E_; ++e) {
      int g = gs[e];
      int t = (g + BM - 1) / BM;
      if (expert < 0 && tile_m < acc + t) {
        int lt = tile_m - acc;
        expert = e;
        row_start = off + lt * BM;
        rows = min(BM, g - lt * BM);
      }
      acc += t;
      off += g;
    }
    if (expert < 0) return;
  }

  const float* WfE = W + (size_t)expert * K_ * N_;

  int tid = threadIdx.x;          // 0..511
  int lane = tid & 63;
  int wave = tid >> 6;            // 0..7
  int wr = wave >> 2;             // 0..1 (M half: 64 rows)
  int wc = wave & 3;              // 0..3 (N quarter: 64 cols)
  int ln15 = lane & 15;
  int n0 = tile_n * BN;

  // ---- fragment read bases (phys slot = logical ^ ((row>>1)&7)) ----
  int slot0 = (((lane >> 4) ^ ((ln15 >> 1) & 7)) << 4);   // ks1 = ^64
  int aBase = wr * 8192 + ln15 * 128;              // + mi*2048
  int bBase = 16384 + wc * 8192 + ln15 * 128;      // + nj*2048

  // ---- A staging: thread stages 16B of each 8KB (64-row) chunk ----
  int soff = tid * 16;
  int crow = tid >> 3;            // 0..63
  int lslot = (tid & 7) ^ ((crow >> 1) & 7);
  int scolA = lslot * 8;
  const unsigned short* aS[2];
  #pragma unroll
  for (int c = 0; c < 2; ++c) {
    int r = c * 64 + crow;
    int gr = r < rows ? r : 0;    // clamp partial M tiles
    aS[c] = Ab + (size_t)(row_start + gr) * K_ + scolA;
  }
#define STG_A(DB, c, kt) \
  gload_lds16(aS[c] + (kt) * 64, smem + (DB) + (c) * 8192 + soff)

  // ---- B fused staging: thread owns rows {nB, nB+1}, k-units kb0 / kb0+4 ----
  int nB = (tid & 127) * 2;       // even row 0..254
  int kb0 = tid >> 7;             // 0..3
  const float* wB = WfE + (size_t)(n0 + nB);       // + k * N_
  int swzB = (nB >> 1) & 7;       // same for rows nB and nB+1
  int bwE0 = 16384 + nB * 128 + ((kb0 ^ swzB) << 4);
  int bwO0 = 16384 + (nB + 1) * 128 + ((kb0 ^ swzB) << 4);
  int bwE1 = 16384 + nB * 128 + (((kb0 + 4) ^ swzB) << 4);
  int bwO1 = 16384 + (nB + 1) * 128 + (((kb0 + 4) ^ swzB) << 4);

  // two reg-set pairs (16 regs each), swapped by tile parity; static-indexed
  float2 sP0[8], sP1[8], sQ0[8], sQ1[8];

#define LOAD_B(arr, KB, KT)                                                   \
  _Pragma("unroll") for (int j = 0; j < 8; ++j)                               \
    arr[j] = *(const float2*)(wB + (size_t)((KT) * 64 + (KB) * 8 + j) * N_);

#define CVT_WRITE(arr, WE, WO, DBN)                                           \
  do {                                                                        \
    us8 oe, oo;                                                               \
    _Pragma("unroll") for (int p = 0; p < 8; ++p) {                           \
      oe[p] = f2bf_hw(arr[p].x);                                              \
      oo[p] = f2bf_hw(arr[p].y);                                              \
    }                                                                         \
    *(us8*)(smem + (DBN) + (WE)) = oe;                                        \
    *(us8*)(smem + (DBN) + (WO)) = oo;                                        \
  } while (0)

  f32x4 acc4[4][4];
  #pragma unroll
  for (int i = 0; i < 4; ++i)
    #pragma unroll
    for (int j = 0; j < 4; ++j)
      acc4[i][j] = f32x4{0.f, 0.f, 0.f, 0.f};

#define DS_A(frag, DB, KS)                                                    \
  _Pragma("unroll") for (int mi = 0; mi < 4; ++mi)                            \
    frag[mi] = *(const bf16x8*)(smem + (DB) + aBase + mi * 2048 +             \
                                (slot0 ^ ((KS) << 6)));
#define DS_B(frag, DB, KS)                                                    \
  _Pragma("unroll") for (int nj = 0; nj < 4; ++nj)                            \
    frag[nj] = *(const bf16x8*)(smem + (DB) + bBase + nj * 2048 +             \
                                (slot0 ^ ((KS) << 6)));
#define MFMA16(af, bf)                                                        \
  __builtin_amdgcn_s_setprio(1);                                              \
  _Pragma("unroll") for (int mi = 0; mi < 4; ++mi)                            \
    _Pragma("unroll") for (int nj = 0; nj < 4; ++nj)                          \
      acc4[mi][nj] = __builtin_amdgcn_mfma_f32_16x16x32_bf16(                 \
          af[mi], bf[nj], acc4[mi][nj], 0, 0, 0);                             \
  __builtin_amdgcn_s_setprio(0);

  // Per K-tile: P0 (ks0), P1 (ks1); 16 MFMA each.
  // L0/L1: sets receiving B(t+2); Wr0/Wr1: sets holding B(t+1) (loaded t-1).
#define TILE2(DB, DBN, Wr0, Wr1, L0, L1, KTA, KTB)                            \
  do {                                                                        \
    bf16x8 af[4], bf[4];                                                      \
    /* P0: ks0 */                                                             \
    DS_A(af, DB, 0); DS_B(bf, DB, 0);                                         \
    STG_A(DBN, 0, KTA); STG_A(DBN, 1, KTA);                                   \
    __builtin_amdgcn_sched_barrier(0);  /* A before B in VMEM FIFO */         \
    LOAD_B(L0, kb0, KTB);                                                     \
    CVT_WRITE(Wr0, bwE0, bwO0, DBN);                                          \
    __builtin_amdgcn_sched_barrier(0);                                        \
    __builtin_amdgcn_s_barrier();                                             \
    asm volatile("s_waitcnt lgkmcnt(0)" ::: "memory");                        \
    __builtin_amdgcn_sched_barrier(0);                                        \
    MFMA16(af, bf);                                                           \
    __builtin_amdgcn_s_barrier();                                             \
    /* P1: ks1 */                                                             \
    DS_A(af, DB, 1); DS_B(bf, DB, 1);                                         \
    LOAD_B(L1, kb0 + 4, KTB);                                                 \
    CVT_WRITE(Wr1, bwE1, bwO1, DBN);                                          \
    __builtin_amdgcn_sched_barrier(0);                                        \
    __builtin_amdgcn_s_barrier();                                             \
    asm volatile("s_waitcnt lgkmcnt(0)" ::: "memory");                        \
    __builtin_amdgcn_sched_barrier(0);                                        \
    MFMA16(af, bf);                                                           \
    asm volatile("s_waitcnt vmcnt(16)" ::: "memory"); /* drain A(t+1) only */ \
    __builtin_amdgcn_s_barrier();                                             \
  } while (0)

  // prologue: A(0) + B(0) (via sP) -> buf0; B(1) -> sQ (left in flight)
  STG_A(0, 0, 0); STG_A(0, 1, 0);
  __builtin_amdgcn_sched_barrier(0);
  LOAD_B(sP0, kb0, 0); LOAD_B(sP1, kb0 + 4, 0);
  __builtin_amdgcn_sched_barrier(0);
  CVT_WRITE(sP0, bwE0, bwO0, 0);    // auto-waits sP loads; drains A(0) too (FIFO)
  CVT_WRITE(sP1, bwE1, bwO1, 0);
  LOAD_B(sQ0, kb0, 1); LOAD_B(sQ1, kb0 + 4, 1);
  __builtin_amdgcn_sched_barrier(0);
  asm volatile("s_waitcnt lgkmcnt(0)" ::: "memory");
  __builtin_amdgcn_s_barrier();

  for (int t2 = 0; t2 < NT; t2 += 2) {
    int k2 = (t2 + 2 >= NT) ? 0 : t2 + 2;   // wrap: dead loads, uniform counts
    int k3 = (t2 + 3 >= NT) ? 0 : t2 + 3;
    // even tile t2: write sQ (B(t2+1)), load sP <- B(t2+2)
    TILE2(0, TILE_B, sQ0, sQ1, sP0, sP1, t2 + 1, k2);
    // odd tile t2+1: write sP (B(t2+2)), load sQ <- B(t2+3)
    TILE2(TILE_B, 0, sP0, sP1, sQ0, sQ1, k2, k3);
  }
#undef TILE2
#undef DS_A
#undef DS_B
#undef MFMA16
#undef STG_A
#undef LOAD_B
#undef CVT_WRITE

  asm volatile("s_waitcnt vmcnt(0)" ::: "memory");  // drain dead tail stages

  // epilogue: C = acc + bias ; C/D layout col=lane&15, row=(lane>>4)*4+reg
  float bv[4];
  #pragma unroll
  for (int nj = 0; nj < 4; ++nj) bv[nj] = bias[n0 + wc * 64 + nj * 16 + ln15];
  #pragma unroll
  for (int mi = 0; mi < 4; ++mi) {
    int r0 = wr * 64 + mi * 16 + (lane >> 4) * 4;
    #pragma unroll
    for (int r = 0; r < 4; ++r) {
      int lr = r0 + r;
      if (lr < rows) {
        float* Cp = C + (size_t)(row_start + lr) * N_ + n0 + wc * 64 + ln15;
        #pragma unroll
        for (int nj = 0; nj < 4; ++nj) Cp[nj * 16] = acc4[mi][nj][r] + bv[nj];
      }
    }
  }
}

// ---------------- naive fp32 fallback (only if workspace too small) ----------------
__global__ __launch_bounds__(256) void moe_naive(const float* __restrict__ A,
                                                 const float* __restrict__ W,
                                                 const int* __restrict__ gs,
                                                 const float* __restrict__ bias,
                                                 float* __restrict__ C) {
  int col = blockIdx.x * 16 + (threadIdx.x & 15);
  int row = blockIdx.y * 16 + (threadIdx.x >> 4);
  int acc = 0, e = E_ - 1;
  for (int i = 0; i < E_; ++i) {
    int g = gs[i];
    if (row >= acc && row < acc + g) { e = i; break; }
    acc += g;
  }
  const float* a = A + (size_t)row * K_;
  const float* w = W + (size_t)e * K_ * N_ + col;
  float s = 0.f;
  for (int k = 0; k < K_; ++k) s += a[k] * w[(size_t)k * N_];
  C[(size_t)row * N_ + col] = s + bias[col];
}

extern "C" void kernel_launch(void* const* d_in, const int* in_sizes, int n_in,
                              void* d_out, int out_size, void* d_ws, size_t ws_size,
                              hipStream_t stream) {
  const float* A = (const float*)d_in[0];
  const float* W = (const float*)d_in[1];
  const int* gs = (const int*)d_in[2];
  const float* bias = (const float*)d_in[3];
  float* C = (float*)d_out;

  const size_t needA = (size_t)M_ * K_ * 2;  // 32 MiB

  (void)hipFuncSetAttribute((const void*)moe_gemm_fused,
                            hipFuncAttributeMaxDynamicSharedMemorySize, LDS_BYTES);

  if (ws_size >= needA) {
    unsigned short* Abf = (unsigned short*)d_ws;
    conv_a<<<2048, 256, 0, stream>>>(A, Abf, (M_ * K_) / 8);
    dim3 gg(N_ / BN, M_ / BM + E_);
    moe_gemm_fused<<<gg, 512, LDS_BYTES, stream>>>(Abf, W, gs, bias, C);
  } else {
    dim3 gn(N_ / 16, M_ / 16);
    moe_naive<<<gn, 256, 0, stream>>>(A, W, gs, bias, C);
  }
}

// Round 11
// 484.773 us; speedup vs baseline: 1.2080x; 1.1867x over previous
//
#include <hip/hip_runtime.h>
#include <stdint.h>

#define E_ 8
#define M_ 8192
#define K_ 2048
#define N_ 8192

#define BM 128
#define BN 128
#define BK 64
#define NT (K_ / BK)        // 32 K-tiles
#define TILE_B 32768        // A 16KB + B 16KB
#define LDS_BYTES 65536     // 2 dbuf x 32KB -> 2 blocks/CU

typedef __attribute__((ext_vector_type(8))) short bf16x8;
typedef __attribute__((ext_vector_type(4))) float f32x4;
typedef __attribute__((ext_vector_type(8))) unsigned short us8;

__device__ __forceinline__ unsigned short f2bf(float f) {
  union { float f; uint32_t u; } v; v.f = f;
  uint32_t u = v.u;
  uint32_t r = (u + 0x7FFFu + ((u >> 16) & 1u)) >> 16;
  return (unsigned short)r;
}

__device__ __forceinline__ void gload_lds16(const void* g, void* l) {
  __builtin_amdgcn_global_load_lds(
      (const __attribute__((address_space(1))) unsigned int*)g,
      (__attribute__((address_space(3))) unsigned int*)l,
      16, 0, 0);
}

// ---------------- fp32 -> bf16, layout preserving (inputs) ----------------
__global__ __launch_bounds__(256) void conv_a(const float* __restrict__ A,
                                              unsigned short* __restrict__ Ab,
                                              int n8) {
  int stride = gridDim.x * blockDim.x;
  for (int idx = blockIdx.x * blockDim.x + threadIdx.x; idx < n8; idx += stride) {
    const float4* p = reinterpret_cast<const float4*>(A) + (size_t)idx * 2;
    float4 x0 = p[0], x1 = p[1];
    us8 o;
    o[0] = f2bf(x0.x); o[1] = f2bf(x0.y); o[2] = f2bf(x0.z); o[3] = f2bf(x0.w);
    o[4] = f2bf(x1.x); o[5] = f2bf(x1.y); o[6] = f2bf(x1.z); o[7] = f2bf(x1.w);
    *reinterpret_cast<us8*>(Ab + (size_t)idx * 8) = o;
  }
}

// ------------- fp32 W[e][K][N] -> bf16 Wt[e][N][K] (transpose) -------------
__global__ __launch_bounds__(256) void conv_wT(const float* __restrict__ W,
                                               unsigned short* __restrict__ Wt,
                                               int e_fixed) {
  __shared__ float t[64][65];
  int tid = threadIdx.x;
  int tx = tid & 63, ty = tid >> 6;
  int n0 = blockIdx.x * 64, k0 = blockIdx.y * 64;
  int e = (gridDim.z > 1) ? blockIdx.z : e_fixed;
  size_t win = (size_t)e * K_ * N_;
  size_t wout = (gridDim.z > 1) ? win : 0;

  #pragma unroll
  for (int r = 0; r < 16; ++r) {
    int kl = r * 4 + ty;
    t[kl][tx] = W[win + (size_t)(k0 + kl) * N_ + n0 + tx];
  }
  __syncthreads();
  int px = tid & 31, py = tid >> 5;
  #pragma unroll
  for (int r = 0; r < 8; ++r) {
    int nl = r * 8 + py;
    unsigned int pack = (unsigned int)f2bf(t[2 * px][nl]) |
                        ((unsigned int)f2bf(t[2 * px + 1][nl]) << 16);
    *reinterpret_cast<unsigned int*>(Wt + wout + (size_t)(n0 + nl) * K_ + k0 + 2 * px) = pack;
  }
}

// ---- grouped bf16 GEMM: 128x128, BK=64, 4 waves, dbuf-2, 2 blocks/CU ----
// LDS dbuf d at d*32768: A @0 (128 rows x 128B), B @16384 (128 rows x 128B).
// Row r: 8 slots of 16B; k-quarter q at phys slot q ^ (r&7) (R2-verified
// conflict-free). Stage chunk = 32 rows = 4KB (one gload_lds per thread).
// Per K-tile: 2 phases (ks0, ks1), 16 MFMA/wave each; all 8 next-tile chunks
// issued at P0 (lag 2 phases); vmcnt(0) at tile end - the co-resident block
// (64KB LDS -> 2 blocks/CU, independent barrier domains) hides the drain.
__global__ __launch_bounds__(256, 2) void moe_gemm_bf16(
    const unsigned short* __restrict__ Ab,   // [M][K] bf16
    const unsigned short* __restrict__ Wt,   // [e][N][K] bf16
    const int* __restrict__ gs,
    const float* __restrict__ bias,
    float* __restrict__ C,
    int only_expert, size_t wt_stride) {
  extern __shared__ char smem[];

  int tile_n = blockIdx.x;
  int tile_m = blockIdx.y;

  int expert = -1, row_start = 0, rows = 0;
  if (only_expert >= 0) {
    int off = 0;
    for (int e = 0; e < only_expert; ++e) off += gs[e];
    int g = gs[only_expert];
    int t0 = tile_m * BM;
    if (t0 >= g) return;
    expert = only_expert;
    row_start = off + t0;
    rows = min(BM, g - t0);
  } else {
    int acc = 0, off = 0;
    for (int e = 0; e < E_; ++e) {
      int g = gs[e];
      int t = (g + BM - 1) / BM;
      if (expert < 0 && tile_m < acc + t) {
        int lt = tile_m - acc;
        expert = e;
        row_start = off + lt * BM;
        rows = min(BM, g - lt * BM);
      }
      acc += t;
      off += g;
    }
    if (expert < 0) return;
  }

  const unsigned short* WtE = Wt + (size_t)expert * wt_stride;

  int tid = threadIdx.x;          // 0..255
  int lane = tid & 63;
  int wave = tid >> 6;            // 0..3
  int wr = wave >> 1;             // 0..1 (M half: 64 rows)
  int wc = wave & 1;              // 0..1 (N half: 64 cols)
  int ln15 = lane & 15;
  int n0 = tile_n * BN;

  // ---- fragment read bases (phys slot = logical ^ (row&7)) ----
  int slot0 = (((lane >> 4) ^ (ln15 & 7)) << 4);   // ks1 = ^64
  int aBase = wr * 8192 + ln15 * 128;              // + mi*2048
  int bBase = 16384 + wc * 8192 + ln15 * 128;      // + nj*2048

  // ---- staging: thread stages 16B of each 4KB (32-row) chunk ----
  int soff = tid * 16;            // dest byte within chunk
  int crow = tid >> 3;            // 0..31
  int lslot = (tid & 7) ^ (crow & 7);
  int scol = lslot * 8;           // bf16 col within 64 (+kt*64 per tile)

  const unsigned short* aS[4];
  const unsigned short* bS[4];
  #pragma unroll
  for (int c = 0; c < 4; ++c) {
    int r = c * 32 + crow;
    int gr = r < rows ? r : 0;     // clamp partial M tiles
    aS[c] = Ab + (size_t)(row_start + gr) * K_ + scol;
    bS[c] = WtE + (size_t)(n0 + r) * K_ + scol;
  }

#define STG_A(DB, c, kt) \
  gload_lds16(aS[c] + (kt) * 64, smem + (DB) + (c) * 4096 + soff)
#define STG_B(DB, c, kt) \
  gload_lds16(bS[c] + (kt) * 64, smem + (DB) + 16384 + (c) * 4096 + soff)
#define STG_ALL(DB, kt)                                                       \
  do {                                                                        \
    STG_B(DB, 0, kt); STG_B(DB, 1, kt); STG_B(DB, 2, kt); STG_B(DB, 3, kt);   \
    STG_A(DB, 0, kt); STG_A(DB, 1, kt); STG_A(DB, 2, kt); STG_A(DB, 3, kt);   \
  } while (0)

  f32x4 acc4[4][4];
  #pragma unroll
  for (int i = 0; i < 4; ++i)
    #pragma unroll
    for (int j = 0; j < 4; ++j)
      acc4[i][j] = f32x4{0.f, 0.f, 0.f, 0.f};

#define DS_A(frag, DB, KS)                                                    \
  _Pragma("unroll") for (int mi = 0; mi < 4; ++mi)                            \
    frag[mi] = *(const bf16x8*)(smem + (DB) + aBase + mi * 2048 +             \
                                (slot0 ^ ((KS) << 6)));
#define DS_B(frag, DB, KS)                                                    \
  _Pragma("unroll") for (int nj = 0; nj < 4; ++nj)                            \
    frag[nj] = *(const bf16x8*)(smem + (DB) + bBase + nj * 2048 +             \
                                (slot0 ^ ((KS) << 6)));
#define MFMA16(af, bf)                                                        \
  __builtin_amdgcn_s_setprio(1);                                              \
  _Pragma("unroll") for (int mi = 0; mi < 4; ++mi)                            \
    _Pragma("unroll") for (int nj = 0; nj < 4; ++nj)                          \
      acc4[mi][nj] = __builtin_amdgcn_mfma_f32_16x16x32_bf16(                 \
          af[mi], bf[nj], acc4[mi][nj], 0, 0, 0);                             \
  __builtin_amdgcn_s_setprio(0);

  // Per K-tile: P0 (ks0) issues next-tile stages; P1 (ks1) drains at end.
#define TILE2(DB, DBN, KTN)                                                   \
  do {                                                                        \
    bf16x8 af[4], bf[4];                                                      \
    /* P0 */                                                                  \
    DS_A(af, DB, 0); DS_B(bf, DB, 0);                                         \
    STG_ALL(DBN, KTN);                                                        \
    __builtin_amdgcn_s_barrier();                                             \
    asm volatile("s_waitcnt lgkmcnt(0)" ::: "memory");                        \
    __builtin_amdgcn_sched_barrier(0);                                        \
    MFMA16(af, bf);                                                           \
    __builtin_amdgcn_s_barrier();                                             \
    /* P1 */                                                                  \
    DS_A(af, DB, 1); DS_B(bf, DB, 1);                                         \
    __builtin_amdgcn_s_barrier();                                             \
    asm volatile("s_waitcnt lgkmcnt(0)" ::: "memory");                        \
    __builtin_amdgcn_sched_barrier(0);                                        \
    MFMA16(af, bf);                                                           \
    asm volatile("s_waitcnt vmcnt(0)" ::: "memory");                          \
    __builtin_amdgcn_s_barrier();                                             \
  } while (0)

  // prologue: stage tile 0 into dbuf0
  STG_ALL(0, 0);
  asm volatile("s_waitcnt vmcnt(0)" ::: "memory");
  __builtin_amdgcn_s_barrier();

  for (int t2 = 0; t2 < NT; t2 += 2) {
    int k2 = (t2 + 2 >= NT) ? 0 : t2 + 2;  // wrap: dead stores, uniform counts
    TILE2(0, TILE_B, t2 + 1);
    TILE2(TILE_B, 0, k2);
  }
#undef TILE2
#undef DS_A
#undef DS_B
#undef MFMA16
#undef STG_A
#undef STG_B
#undef STG_ALL

  // epilogue: C = acc + bias ; C/D layout col=lane&15, row=(lane>>4)*4+reg
  float bv[4];
  #pragma unroll
  for (int nj = 0; nj < 4; ++nj) bv[nj] = bias[n0 + wc * 64 + nj * 16 + ln15];
  #pragma unroll
  for (int mi = 0; mi < 4; ++mi) {
    int r0 = wr * 64 + mi * 16 + (lane >> 4) * 4;
    #pragma unroll
    for (int r = 0; r < 4; ++r) {
      int lr = r0 + r;
      if (lr < rows) {
        float* Cp = C + (size_t)(row_start + lr) * N_ + n0 + wc * 64 + ln15;
        #pragma unroll
        for (int nj = 0; nj < 4; ++nj) Cp[nj * 16] = acc4[mi][nj][r] + bv[nj];
      }
    }
  }
}

// ---------------- naive fp32 fallback (only if workspace too small) ----------------
__global__ __launch_bounds__(256) void moe_naive(const float* __restrict__ A,
                                                 const float* __restrict__ W,
                                                 const int* __restrict__ gs,
                                                 const float* __restrict__ bias,
                                                 float* __restrict__ C) {
  int col = blockIdx.x * 16 + (threadIdx.x & 15);
  int row = blockIdx.y * 16 + (threadIdx.x >> 4);
  int acc = 0, e = E_ - 1;
  for (int i = 0; i < E_; ++i) {
    int g = gs[i];
    if (row >= acc && row < acc + g) { e = i; break; }
    acc += g;
  }
  const float* a = A + (size_t)row * K_;
  const float* w = W + (size_t)e * K_ * N_ + col;
  float s = 0.f;
  for (int k = 0; k < K_; ++k) s += a[k] * w[(size_t)k * N_];
  C[(size_t)row * N_ + col] = s + bias[col];
}

extern "C" void kernel_launch(void* const* d_in, const int* in_sizes, int n_in,
                              void* d_out, int out_size, void* d_ws, size_t ws_size,
                              hipStream_t stream) {
  const float* A = (const float*)d_in[0];
  const float* W = (const float*)d_in[1];
  const int* gs = (const int*)d_in[2];
  const float* bias = (const float*)d_in[3];
  float* C = (float*)d_out;

  const size_t needA = (size_t)M_ * K_ * 2;          // 32 MiB
  const size_t needWall = (size_t)E_ * K_ * N_ * 2;  // 256 MiB
  const size_t needW1 = (size_t)K_ * N_ * 2;         // 32 MiB

  (void)hipFuncSetAttribute((const void*)moe_gemm_bf16,
                            hipFuncAttributeMaxDynamicSharedMemorySize, LDS_BYTES);

  if (ws_size >= needA + needWall) {
    unsigned short* Abf = (unsigned short*)d_ws;
    unsigned short* Wtb = (unsigned short*)((char*)d_ws + needA);
    conv_a<<<2048, 256, 0, stream>>>(A, Abf, (M_ * K_) / 8);
    dim3 gw(N_ / 64, K_ / 64, E_);
    conv_wT<<<gw, 256, 0, stream>>>(W, Wtb, 0);
    dim3 gg(N_ / BN, M_ / BM + E_);
    moe_gemm_bf16<<<gg, 256, LDS_BYTES, stream>>>(Abf, Wtb, gs, bias, C, -1, (size_t)N_ * K_);
  } else if (ws_size >= needA + needW1) {
    unsigned short* Abf = (unsigned short*)d_ws;
    unsigned short* Wtb = (unsigned short*)((char*)d_ws + needA);
    conv_a<<<2048, 256, 0, stream>>>(A, Abf, (M_ * K_) / 8);
    for (int e = 0; e < E_; ++e) {
      dim3 gw(N_ / 64, K_ / 64, 1);
      conv_wT<<<gw, 256, 0, stream>>>(W, Wtb, e);
      dim3 gg(N_ / BN, M_ / BM);
      moe_gemm_bf16<<<gg, 256, LDS_BYTES, stream>>>(Abf, Wtb, gs, bias, C, e, 0);
    }
  } else {
    dim3 gn(N_ / 16, M_ / 16);
    moe_naive<<<gn, 256, 0, stream>>>(A, W, gs, bias, C);
  }
}

// Round 12
// 439.330 us; speedup vs baseline: 1.3330x; 1.1034x over previous
//
#include <hip/hip_runtime.h>
#include <stdint.h>

#define E_ 8
#define M_ 8192
#define K_ 2048
#define N_ 8192

#define BM 256
#define BN 256
#define BK 64
#define NT (K_ / BK)        // 32 K-tiles
#define LDS_BYTES 131072    // 2 dbuf x 64KB

typedef __attribute__((ext_vector_type(8))) short bf16x8;
typedef __attribute__((ext_vector_type(4))) float f32x4;
typedef __attribute__((ext_vector_type(8))) unsigned short us8;

__device__ __forceinline__ unsigned short f2bf(float f) {
  union { float f; uint32_t u; } v; v.f = f;
  uint32_t u = v.u;
  uint32_t r = (u + 0x7FFFu + ((u >> 16) & 1u)) >> 16;
  return (unsigned short)r;
}

__device__ __forceinline__ void gload_lds16(const void* g, void* l) {
  __builtin_amdgcn_global_load_lds(
      (const __attribute__((address_space(1))) unsigned int*)g,
      (__attribute__((address_space(3))) unsigned int*)l,
      16, 0, 0);
}

// ---------------- fp32 -> bf16, layout preserving (inputs) ----------------
__global__ __launch_bounds__(256) void conv_a(const float* __restrict__ A,
                                              unsigned short* __restrict__ Ab,
                                              int n8) {
  int stride = gridDim.x * blockDim.x;
  for (int idx = blockIdx.x * blockDim.x + threadIdx.x; idx < n8; idx += stride) {
    const float4* p = reinterpret_cast<const float4*>(A) + (size_t)idx * 2;
    float4 x0 = p[0], x1 = p[1];
    us8 o;
    o[0] = f2bf(x0.x); o[1] = f2bf(x0.y); o[2] = f2bf(x0.z); o[3] = f2bf(x0.w);
    o[4] = f2bf(x1.x); o[5] = f2bf(x1.y); o[6] = f2bf(x1.z); o[7] = f2bf(x1.w);
    *reinterpret_cast<us8*>(Ab + (size_t)idx * 8) = o;
  }
}

// ------------- fp32 W[e][K][N] -> bf16 Wt[e][N][K] (transpose) -------------
__global__ __launch_bounds__(256) void conv_wT(const float* __restrict__ W,
                                               unsigned short* __restrict__ Wt,
                                               int e_fixed) {
  __shared__ float t[64][65];
  int tid = threadIdx.x;
  int tx = tid & 63, ty = tid >> 6;
  int n0 = blockIdx.x * 64, k0 = blockIdx.y * 64;
  int e = (gridDim.z > 1) ? blockIdx.z : e_fixed;
  size_t win = (size_t)e * K_ * N_;
  size_t wout = (gridDim.z > 1) ? win : 0;

  #pragma unroll
  for (int r = 0; r < 16; ++r) {
    int kl = r * 4 + ty;
    t[kl][tx] = W[win + (size_t)(k0 + kl) * N_ + n0 + tx];
  }
  __syncthreads();
  int px = tid & 31, py = tid >> 5;
  #pragma unroll
  for (int r = 0; r < 8; ++r) {
    int nl = r * 8 + py;
    unsigned int pack = (unsigned int)f2bf(t[2 * px][nl]) |
                        ((unsigned int)f2bf(t[2 * px + 1][nl]) << 16);
    *reinterpret_cast<unsigned int*>(Wt + wout + (size_t)(n0 + nl) * K_ + k0 + 2 * px) = pack;
  }
}

// ---- grouped bf16 GEMM: 256x256, BK=64, dbuf-2, ONE barrier per K-tile ----
// LDS dbuf d at d*65536: A @0 (256 rows x 128B), B @32768 (256 rows x 128B).
// Row r: 8 slots of 16B; k-quarter q at phys slot q ^ (r&7) (R2/R5-verified
// 0-conflict layout). Per K-tile: issue all 8 next-tile stages FIRST
// (sched_barrier-pinned), then 24 ds_read + 64 MFMA compiler-interleaved
// (fine-grained lgkmcnt left to the compiler - no inline pins), then
// vmcnt(0) (stages ~900cy old by then) + a single s_barrier.
// Hazard proof for 1 barrier/tile: all in-tile reads hit the current buffer;
// stages target the other buffer whose readers (tile t-1 MFMAs) drained
// their lgkm before t-1's end barrier.
__global__ __launch_bounds__(512, 2) void moe_gemm_bf16(
    const unsigned short* __restrict__ Ab,   // [M][K] bf16
    const unsigned short* __restrict__ Wt,   // [e][N][K] bf16
    const int* __restrict__ gs,
    const float* __restrict__ bias,
    float* __restrict__ C,
    int only_expert, size_t wt_stride) {
  extern __shared__ char smem[];

  int tile_n = blockIdx.x;
  int tile_m = blockIdx.y;

  int expert = -1, row_start = 0, rows = 0;
  if (only_expert >= 0) {
    int off = 0;
    for (int e = 0; e < only_expert; ++e) off += gs[e];
    int g = gs[only_expert];
    int t0 = tile_m * BM;
    if (t0 >= g) return;
    expert = only_expert;
    row_start = off + t0;
    rows = min(BM, g - t0);
  } else {
    int acc = 0, off = 0;
    for (int e = 0; e < E_; ++e) {
      int g = gs[e];
      int t = (g + BM - 1) / BM;
      if (expert < 0 && tile_m < acc + t) {
        int lt = tile_m - acc;
        expert = e;
        row_start = off + lt * BM;
        rows = min(BM, g - lt * BM);
      }
      acc += t;
      off += g;
    }
    if (expert < 0) return;
  }

  const unsigned short* WtE = Wt + (size_t)expert * wt_stride;

  int tid = threadIdx.x;          // 0..511
  int lane = tid & 63;
  int wave = tid >> 6;            // 0..7
  int wr = wave >> 2;             // 0..1 (M half)
  int wc = wave & 3;              // 0..3 (N quarter)
  int bh = wc >> 1;               // B 128-half
  int ln15 = lane & 15;
  int n0 = tile_n * BN;

  // ---- fragment read bases (phys slot = logical ^ (row&7)) ----
  int slot0 = (((lane >> 4) ^ (ln15 & 7)) << 4);   // ks1 = ^64
  int aBase = wr * 16384 + ln15 * 128;             // + mh*8192 + mi*2048
  int bBase = 32768 + bh * 16384 + (wc & 1) * 8192 + ln15 * 128;  // + nj*2048

  // ---- staging precompute: thread stages 16B of each 8KB (64-row) chunk ----
  int soff = tid * 16;
  int crow = tid >> 3;            // 0..63
  int lslot = (tid & 7) ^ (crow & 7);
  int scol = lslot * 8;

  const unsigned short* aS[4];
  const unsigned short* bS[4];
  #pragma unroll
  for (int c = 0; c < 4; ++c) {
    int r = c * 64 + crow;
    int gr = r < rows ? r : 0;     // clamp partial M tiles
    aS[c] = Ab + (size_t)(row_start + gr) * K_ + scol;
    bS[c] = WtE + (size_t)(n0 + r) * K_ + scol;
  }

#define STG_A(DB, c, kt) \
  gload_lds16(aS[c] + (kt) * 64, smem + (DB) + (c) * 8192 + soff)
#define STG_B(DB, c, kt) \
  gload_lds16(bS[c] + (kt) * 64, smem + (DB) + 32768 + (c) * 8192 + soff)
#define STG_ALL(DB, kt)                                                       \
  do {                                                                        \
    STG_B(DB, 0, kt); STG_B(DB, 1, kt); STG_B(DB, 2, kt); STG_B(DB, 3, kt);   \
    STG_A(DB, 0, kt); STG_A(DB, 1, kt); STG_A(DB, 2, kt); STG_A(DB, 3, kt);   \
  } while (0)

  f32x4 acc4[8][4];
  #pragma unroll
  for (int i = 0; i < 8; ++i)
    #pragma unroll
    for (int j = 0; j < 4; ++j)
      acc4[i][j] = f32x4{0.f, 0.f, 0.f, 0.f};

  // One compiler-scheduled region per K-tile; ONE barrier per K-tile.
#define TILE1(DB, DBN, KTN)                                                   \
  do {                                                                        \
    STG_ALL(DBN, KTN);                                                        \
    __builtin_amdgcn_sched_barrier(0);  /* stages stay first */               \
    __builtin_amdgcn_s_setprio(1);                                            \
    _Pragma("unroll") for (int ks = 0; ks < 2; ++ks) {                        \
      bf16x8 bfr[4];                                                          \
      _Pragma("unroll") for (int nj = 0; nj < 4; ++nj)                        \
        bfr[nj] = *(const bf16x8*)(smem + (DB) + bBase + nj * 2048 +          \
                                   (slot0 ^ (ks << 6)));                      \
      _Pragma("unroll") for (int mh = 0; mh < 2; ++mh) {                      \
        bf16x8 afr[4];                                                        \
        _Pragma("unroll") for (int mi = 0; mi < 4; ++mi)                      \
          afr[mi] = *(const bf16x8*)(smem + (DB) + aBase + mh * 8192 +        \
                                     mi * 2048 + (slot0 ^ (ks << 6)));        \
        _Pragma("unroll") for (int mi = 0; mi < 4; ++mi)                      \
          _Pragma("unroll") for (int nj = 0; nj < 4; ++nj)                    \
            acc4[mh * 4 + mi][nj] = __builtin_amdgcn_mfma_f32_16x16x32_bf16(  \
                afr[mi], bfr[nj], acc4[mh * 4 + mi][nj], 0, 0, 0);            \
      }                                                                       \
    }                                                                         \
    __builtin_amdgcn_s_setprio(0);                                            \
    asm volatile("s_waitcnt vmcnt(0)" ::: "memory");                          \
    __builtin_amdgcn_s_barrier();                                             \
  } while (0)

  // prologue: stage tile 0 into dbuf0
  STG_ALL(0, 0);
  asm volatile("s_waitcnt vmcnt(0)" ::: "memory");
  __builtin_amdgcn_s_barrier();

  for (int t2 = 0; t2 < NT; t2 += 2) {
    int k2 = (t2 + 2 >= NT) ? 0 : t2 + 2;  // wrap: dead stores, uniform counts
    TILE1(0, 65536, t2 + 1);
    TILE1(65536, 0, k2);
  }
#undef TILE1
#undef STG_A
#undef STG_B
#undef STG_ALL

  // epilogue: C = acc + bias ; C/D layout col=lane&15, row=(lane>>4)*4+reg
  float bv[4];
  #pragma unroll
  for (int nj = 0; nj < 4; ++nj) bv[nj] = bias[n0 + wc * 64 + nj * 16 + ln15];
  #pragma unroll
  for (int mi = 0; mi < 8; ++mi) {
    int r0 = wr * 128 + mi * 16 + (lane >> 4) * 4;
    #pragma unroll
    for (int r = 0; r < 4; ++r) {
      int lr = r0 + r;
      if (lr < rows) {
        float* Cp = C + (size_t)(row_start + lr) * N_ + n0 + wc * 64 + ln15;
        #pragma unroll
        for (int nj = 0; nj < 4; ++nj) Cp[nj * 16] = acc4[mi][nj][r] + bv[nj];
      }
    }
  }
}

// ---------------- naive fp32 fallback (only if workspace too small) ----------------
__global__ __launch_bounds__(256) void moe_naive(const float* __restrict__ A,
                                                 const float* __restrict__ W,
                                                 const int* __restrict__ gs,
                                                 const float* __restrict__ bias,
                                                 float* __restrict__ C) {
  int col = blockIdx.x * 16 + (threadIdx.x & 15);
  int row = blockIdx.y * 16 + (threadIdx.x >> 4);
  int acc = 0, e = E_ - 1;
  for (int i = 0; i < E_; ++i) {
    int g = gs[i];
    if (row >= acc && row < acc + g) { e = i; break; }
    acc += g;
  }
  const float* a = A + (size_t)row * K_;
  const float* w = W + (size_t)e * K_ * N_ + col;
  float s = 0.f;
  for (int k = 0; k < K_; ++k) s += a[k] * w[(size_t)k * N_];
  C[(size_t)row * N_ + col] = s + bias[col];
}

extern "C" void kernel_launch(void* const* d_in, const int* in_sizes, int n_in,
                              void* d_out, int out_size, void* d_ws, size_t ws_size,
                              hipStream_t stream) {
  const float* A = (const float*)d_in[0];
  const float* W = (const float*)d_in[1];
  const int* gs = (const int*)d_in[2];
  const float* bias = (const float*)d_in[3];
  float* C = (float*)d_out;

  const size_t needA = (size_t)M_ * K_ * 2;          // 32 MiB
  const size_t needWall = (size_t)E_ * K_ * N_ * 2;  // 256 MiB
  const size_t needW1 = (size_t)K_ * N_ * 2;         // 32 MiB

  (void)hipFuncSetAttribute((const void*)moe_gemm_bf16,
                            hipFuncAttributeMaxDynamicSharedMemorySize, LDS_BYTES);

  if (ws_size >= needA + needWall) {
    unsigned short* Abf = (unsigned short*)d_ws;
    unsigned short* Wtb = (unsigned short*)((char*)d_ws + needA);
    conv_a<<<2048, 256, 0, stream>>>(A, Abf, (M_ * K_) / 8);
    dim3 gw(N_ / 64, K_ / 64, E_);
    conv_wT<<<gw, 256, 0, stream>>>(W, Wtb, 0);
    dim3 gg(N_ / BN, M_ / BM + E_);
    moe_gemm_bf16<<<gg, 512, LDS_BYTES, stream>>>(Abf, Wtb, gs, bias, C, -1, (size_t)N_ * K_);
  } else if (ws_size >= needA + needW1) {
    unsigned short* Abf = (unsigned short*)d_ws;
    unsigned short* Wtb = (unsigned short*)((char*)d_ws + needA);
    conv_a<<<2048, 256, 0, stream>>>(A, Abf, (M_ * K_) / 8);
    for (int e = 0; e < E_; ++e) {
      dim3 gw(N_ / 64, K_ / 64, 1);
      conv_wT<<<gw, 256, 0, stream>>>(W, Wtb, e);
      dim3 gg(N_ / BN, M_ / BM);
      moe_gemm_bf16<<<gg, 512, LDS_BYTES, stream>>>(Abf, Wtb, gs, bias, C, e, 0);
    }
  } else {
    dim3 gn(N_ / 16, M_ / 16);
    moe_naive<<<gn, 256, 0, stream>>>(A, W, gs, bias, C);
  }
}